// Round 7
// baseline (29262.482 us; speedup 1.0000x reference)
//
#include <hip/hip_runtime.h>
#include <stdint.h>

// DecoderRNN R7: LLC write-through data path. 2-layer GRU, H=512, B=64, T=1024.
// 128 WGs x 256 threads, phase-specialized (role = wg>>5, j = wg&31):
//   role 0: phase A: h0n = GRU0(h0c, prev); reduces yout partials -> prev
//   role 1: phase A: gh1raw = h1c @ Whh1^T
//   role 2: phase B: h1n = GRU1(h0n @ Wih1^T, gh1raw, h1c)
//   role 3: phase C: y-partials: wo2 . relu(Wo1 h1n + bo1) -> yout
// R7 change vs R6: ALL cross-WG global data (h states, gh1raw, yout) is written
// with RELAXED agent-scope atomic stores (write-through to LLC, L2 stays clean)
// so the barrier's release wbl2 / acquire inv become ~no-ops. h stored packed
// as (bf16hi<<16)|bf16lo in one uint; readers unpack with v_perm_b32.
// Two-level epoch barrier (master WG0), 3/step.

#define NWG 128
#define NT  256
#define TT  1024

typedef unsigned short ushort;
typedef unsigned int   uint;
typedef __attribute__((ext_vector_type(8))) short short8;
typedef __attribute__((ext_vector_type(4))) float f32x4;
typedef __attribute__((ext_vector_type(4))) uint  uint4v;

struct __align__(16) Smem {
  ushort wpl[2][48*520];   // [hi|lo][row r=g*16+n][k], row stride 520
  float  gictx[3*16*68];   // role0: ctx@Wih0^T + bih0 (+bhh0 r,z), [g][n][b] pad 68
  float  wcol[3][16];      // role0: Wih0[:,512]
  float  bsumR[16], bsumZ[16], binN[16], bhnN[16];
  float  bo1v[16], wo2v[16];
  float  prevS[64];
};

__device__ __forceinline__ float sigm(float x){ return 1.f/(1.f + expf(-x)); }
__device__ __forceinline__ float bf2f(ushort h){ return __uint_as_float(((uint)h)<<16); }
__device__ __forceinline__ ushort bfrnd(float x){
  uint u = __float_as_uint(x);
  return (ushort)((u + 0x7fffu + ((u>>16)&1u)) >> 16);
}
__device__ __forceinline__ float unpk(uint p){
  return bf2f((ushort)(p >> 16)) + bf2f((ushort)(p & 0xffffu));
}
__device__ __forceinline__ uint pkh(float h){
  ushort hb = bfrnd(h);
  ushort lb = bfrnd(h - bf2f(hb));
  return ((uint)hb << 16) | (uint)lb;
}
// extract hi/lo bf16 short8 from 8 packed uints (1 v_perm per 2 elements)
__device__ __forceinline__ short8 hi8(uint4v a, uint4v b){
  uint d0 = __builtin_amdgcn_perm(a.y, a.x, 0x07060302u);
  uint d1 = __builtin_amdgcn_perm(a.w, a.z, 0x07060302u);
  uint d2 = __builtin_amdgcn_perm(b.y, b.x, 0x07060302u);
  uint d3 = __builtin_amdgcn_perm(b.w, b.z, 0x07060302u);
  return __builtin_bit_cast(short8, (uint4v){d0,d1,d2,d3});
}
__device__ __forceinline__ short8 lo8(uint4v a, uint4v b){
  uint d0 = __builtin_amdgcn_perm(a.y, a.x, 0x05040100u);
  uint d1 = __builtin_amdgcn_perm(a.w, a.z, 0x05040100u);
  uint d2 = __builtin_amdgcn_perm(b.y, b.x, 0x05040100u);
  uint d3 = __builtin_amdgcn_perm(b.w, b.z, 0x05040100u);
  return __builtin_bit_cast(short8, (uint4v){d0,d1,d2,d3});
}
#define STW(p, v) __hip_atomic_store((p), (v), __ATOMIC_RELAXED, __HIP_MEMORY_SCOPE_AGENT)

__device__ __forceinline__ void gbar(int* slots, int* epoch, int w, int tid, int e){
  __syncthreads();
  if (tid == 0)
    __hip_atomic_store(&slots[w], e, __ATOMIC_RELEASE, __HIP_MEMORY_SCOPE_AGENT);
  if (w == 0 && tid < 64){
    for(;;){
      int m0 = __hip_atomic_load(&slots[tid*2+0], __ATOMIC_RELAXED, __HIP_MEMORY_SCOPE_AGENT);
      int m1 = __hip_atomic_load(&slots[tid*2+1], __ATOMIC_RELAXED, __HIP_MEMORY_SCOPE_AGENT);
      if (__all(min(m0,m1) >= e)) break;
      __builtin_amdgcn_s_sleep(1);
    }
    if (tid == 0){
      __builtin_amdgcn_fence(__ATOMIC_ACQUIRE, "agent");
      __hip_atomic_store(epoch, e, __ATOMIC_RELEASE, __HIP_MEMORY_SCOPE_AGENT);
    }
  }
  if (tid == 0){
    while (__hip_atomic_load(epoch, __ATOMIC_RELAXED, __HIP_MEMORY_SCOPE_AGENT) < e)
      __builtin_amdgcn_s_sleep(1);
    __builtin_amdgcn_fence(__ATOMIC_ACQUIRE, "agent");
  }
  __syncthreads();
}

// issue all 32 packed loads first (one LLC RTT), then per-chunk unpack+MFMA
#define LDONLY(P, i) \
  uint4v pa##i = *(const uint4v*)((P) + aoff + (i)*32); \
  uint4v pb##i = *(const uint4v*)((P) + aoff + (i)*32 + 4);
#define DECL_LOADS(P) LDONLY(P,0) LDONLY(P,1) LDONLY(P,2) LDONLY(P,3) \
  LDONLY(P,4) LDONLY(P,5) LDONLY(P,6) LDONLY(P,7) LDONLY(P,8) LDONLY(P,9) \
  LDONLY(P,10) LDONLY(P,11) LDONLY(P,12) LDONLY(P,13) LDONLY(P,14) LDONLY(P,15)

#define MS3(i) { \
  short8 AH_ = hi8(pa##i, pb##i); \
  short8 AL_ = lo8(pa##i, pb##i); \
  const int ko_ = (i)*32 + q*8; \
  short8 bh_ = *(const short8*)(&S.wpl[0][(col)*520 + ko_]); \
  short8 bl_ = *(const short8*)(&S.wpl[1][(col)*520 + ko_]); \
  acc0 = __builtin_amdgcn_mfma_f32_16x16x32_bf16(AH_, bh_, acc0, 0,0,0); \
  acc0 = __builtin_amdgcn_mfma_f32_16x16x32_bf16(AL_, bh_, acc0, 0,0,0); \
  acc0 = __builtin_amdgcn_mfma_f32_16x16x32_bf16(AH_, bl_, acc0, 0,0,0); \
  bh_ = *(const short8*)(&S.wpl[0][(16+col)*520 + ko_]); \
  bl_ = *(const short8*)(&S.wpl[1][(16+col)*520 + ko_]); \
  acc1 = __builtin_amdgcn_mfma_f32_16x16x32_bf16(AH_, bh_, acc1, 0,0,0); \
  acc1 = __builtin_amdgcn_mfma_f32_16x16x32_bf16(AL_, bh_, acc1, 0,0,0); \
  acc1 = __builtin_amdgcn_mfma_f32_16x16x32_bf16(AH_, bl_, acc1, 0,0,0); \
  bh_ = *(const short8*)(&S.wpl[0][(32+col)*520 + ko_]); \
  bl_ = *(const short8*)(&S.wpl[1][(32+col)*520 + ko_]); \
  acc2 = __builtin_amdgcn_mfma_f32_16x16x32_bf16(AH_, bh_, acc2, 0,0,0); \
  acc2 = __builtin_amdgcn_mfma_f32_16x16x32_bf16(AL_, bh_, acc2, 0,0,0); \
  acc2 = __builtin_amdgcn_mfma_f32_16x16x32_bf16(AH_, bl_, acc2, 0,0,0); }

#define MS1(i) { \
  short8 AH_ = hi8(pa##i, pb##i); \
  short8 AL_ = lo8(pa##i, pb##i); \
  const int ko_ = (i)*32 + q*8; \
  short8 bh_ = *(const short8*)(&S.wpl[0][(col)*520 + ko_]); \
  short8 bl_ = *(const short8*)(&S.wpl[1][(col)*520 + ko_]); \
  acc0 = __builtin_amdgcn_mfma_f32_16x16x32_bf16(AH_, bh_, acc0, 0,0,0); \
  acc0 = __builtin_amdgcn_mfma_f32_16x16x32_bf16(AL_, bh_, acc0, 0,0,0); \
  acc0 = __builtin_amdgcn_mfma_f32_16x16x32_bf16(AH_, bl_, acc0, 0,0,0); }

#define RUN16(M) M(0) M(1) M(2) M(3) M(4) M(5) M(6) M(7) \
                 M(8) M(9) M(10) M(11) M(12) M(13) M(14) M(15)

extern "C" __global__ void __launch_bounds__(NT, 1)
decoder_rnn(const float* __restrict__ ctx,   // [64][512]
            const float* __restrict__ Wih0,  // [1536][513] (row stride 513!)
            const float* __restrict__ Whh0,
            const float* __restrict__ bih0,
            const float* __restrict__ bhh0g,
            const float* __restrict__ Wih1,
            const float* __restrict__ Whh1,
            const float* __restrict__ bih1g,
            const float* __restrict__ bhh1g,
            const float* __restrict__ Wo1,
            const float* __restrict__ bo1g,
            const float* __restrict__ Wo2,
            const float* __restrict__ bo2g,
            float* __restrict__ out,         // [64*1024 y][65536 h_i]
            float* __restrict__ ws)
{
  extern __shared__ char smem_raw[];
  Smem& S = *reinterpret_cast<Smem*>(smem_raw);
  const int tid = threadIdx.x;
  const int wg  = blockIdx.x;

  // ws (uint units): h0pk 2x32768 | h1pk 32768 ; (float units from 98304):
  // gh1raw 32x3072 | yout 2x2048 | slots/epoch
  uint*  hpk    = (uint*)ws;
  float* gh1raw = (float*)ws + 98304;
  float* yout   = (float*)ws + 196608;
  int*   slots  = (int*)((float*)ws + 200704);
  int*   epoch  = slots + NWG;

  const float bo2v = bo2g[0];

  // ---------------- init: zeros (write-through) ----------------
  for (int i = wg*NT + tid; i < 32768; i += NWG*NT){
    STW(hpk + i, 0u);            // h0pk buf0
    STW(hpk + 65536 + i, 0u);    // h1pk
  }

  // ---------------- init: weights -> LDS planes ----------------
  const int role = wg >> 5;
  const int j    = wg & 31;
  if (role != 3){
    const float* Wsrc = (role == 0) ? Whh0 : (role == 1) ? Whh1 : Wih1;
    for (int i = tid; i < 48*512; i += NT){
      int r = i >> 9, k = i & 511;
      int g = r >> 4, n = r & 15;
      float wv = Wsrc[(size_t)(g*512 + 16*j + n)*512 + k];
      ushort hh = bfrnd(wv);
      S.wpl[0][r*520 + k] = hh;
      S.wpl[1][r*520 + k] = bfrnd(wv - bf2f(hh));
    }
  } else {
    for (int i = tid; i < 16*512; i += NT){
      int r = i >> 9, k = i & 511;
      float wv = Wo1[(size_t)(16*j + r)*512 + k];
      ushort hh = bfrnd(wv);
      S.wpl[0][r*520 + k] = hh;
      S.wpl[1][r*520 + k] = bfrnd(wv - bf2f(hh));
    }
    if (tid < 16){ S.bo1v[tid] = bo1g[16*j + tid]; S.wo2v[tid] = Wo2[16*j + tid]; }
  }
  if (role == 0){
    if (tid < 48){
      int g = tid >> 4, n = tid & 15;
      S.wcol[g][n] = Wih0[(size_t)(g*512 + 16*j + n)*513 + 512];
    }
    if (tid < 16) S.bhnN[tid] = bhh0g[2*512 + 16*j + tid];
    for (int idx = tid; idx < 3072; idx += NT){
      int r = idx >> 6, b = idx & 63;
      int g = r >> 4, n = r & 15;
      int grow = g*512 + 16*j + n;
      const float* wr = Wih0 + (size_t)grow*513;
      const float* cx = ctx  + (size_t)b*512;
      float s = bih0[grow];
      if (g < 2) s += bhh0g[grow];
      #pragma unroll 4
      for (int k = 0; k < 512; ++k) s += wr[k]*cx[k];
      S.gictx[g*1088 + n*68 + b] = s;
    }
  }
  if (role == 2 && tid < 16){
    int n = tid;
    S.bsumR[n] = bih1g[16*j + n]       + bhh1g[16*j + n];
    S.bsumZ[n] = bih1g[512 + 16*j + n] + bhh1g[512 + 16*j + n];
    S.binN[n]  = bih1g[1024 + 16*j + n];
    S.bhnN[n]  = bhh1g[1024 + 16*j + n];
  }

  gbar(slots, epoch, wg, tid, 1);

  const int v   = tid >> 6;
  const int l   = tid & 63;
  const int q   = l >> 4;
  const int col = l & 15;
  const int aoff = (16*v + col)*512 + q*8;
  const int b0w  = 16*v + 4*q;
  const int ng   = 16*j + col;

  for (int t = 0; t < TT; ++t){
    const int r0 = t & 1, w0 = r0 ^ 1;

    // ================= phase A =================
    if (role == 0){
      const uint* rP = hpk + r0*32768;
      uint*       wP = hpk + w0*32768;
      f32x4 acc0={0,0,0,0}, acc1={0,0,0,0}, acc2={0,0,0,0};
      DECL_LOADS(rP)
      uint pk0 = rP[(b0w+0)*512+ng], pk1 = rP[(b0w+1)*512+ng],
           pk2 = rP[(b0w+2)*512+ng], pk3 = rP[(b0w+3)*512+ng];
      if (tid < 64){
        float s = 0.f;
        if (t > 0){
          const float* yp = yout + ((t-1)&1)*2048 + tid;
          #pragma unroll
          for (int jj = 0; jj < 32; ++jj) s += yp[jj*64];
        }
        float pv = fmaxf(s + bo2v, 0.f);
        S.prevS[tid] = pv;
        if (wg == 0 && t > 0) out[(size_t)tid*TT + (t-1)] = pv;
      }
      RUN16(MS3)
      __syncthreads();
      f32x4 pv4 = *(const f32x4*)&S.prevS[b0w];
      f32x4 gR = *(const f32x4*)&S.gictx[0*1088 + col*68 + b0w];
      f32x4 gZ = *(const f32x4*)&S.gictx[1*1088 + col*68 + b0w];
      f32x4 gN = *(const f32x4*)&S.gictx[2*1088 + col*68 + b0w];
      float wc0 = S.wcol[0][col], wc1 = S.wcol[1][col], wc2 = S.wcol[2][col];
      float bhn = S.bhnN[col];
      #define E0(i, PK) { \
        float hold = unpk(PK); \
        float rr = sigm(gR[i] + pv4[i]*wc0 + acc0[i]); \
        float zz = sigm(gZ[i] + pv4[i]*wc1 + acc1[i]); \
        float nn = tanhf(gN[i] + pv4[i]*wc2 + rr*(acc2[i] + bhn)); \
        float h = (1.f-zz)*nn + zz*hold; \
        STW(wP + (size_t)(b0w+(i))*512 + ng, pkh(h)); }
      E0(0,pk0) E0(1,pk1) E0(2,pk2) E0(3,pk3)
      #undef E0
    } else if (role == 1){
      const uint* hp1 = hpk + 65536;
      f32x4 acc0={0,0,0,0}, acc1={0,0,0,0}, acc2={0,0,0,0};
      DECL_LOADS(hp1)
      RUN16(MS3)
      float* gp = gh1raw + (size_t)j*3072 + v*256 + l*4;
      #pragma unroll
      for (int e = 0; e < 4; ++e){
        STW(gp + e,        acc0[e]);
        STW(gp + 1024 + e, acc1[e]);
        STW(gp + 2048 + e, acc2[e]);
      }
    }
    gbar(slots, epoch, wg, tid, 3*t + 2);

    // ================= phase B =================
    if (role == 2){
      const uint* rP = hpk + w0*32768;   // h0n
      uint*       p1 = hpk + 65536;      // h1 (in place)
      f32x4 acc0={0,0,0,0}, acc1={0,0,0,0}, acc2={0,0,0,0};
      DECL_LOADS(rP)
      const float* gp = gh1raw + (size_t)j*3072 + v*256 + l*4;
      f32x4 hR = *(const f32x4*)(gp + 0);
      f32x4 hZ = *(const f32x4*)(gp + 1024);
      f32x4 hN = *(const f32x4*)(gp + 2048);
      uint pk0 = p1[(b0w+0)*512+ng], pk1 = p1[(b0w+1)*512+ng],
           pk2 = p1[(b0w+2)*512+ng], pk3 = p1[(b0w+3)*512+ng];
      RUN16(MS3)
      float bsR = S.bsumR[col], bsZ = S.bsumZ[col], biN = S.binN[col], bhN = S.bhnN[col];
      #define E1(i, PK) { \
        float hold = unpk(PK); \
        float r1 = sigm(acc0[i] + hR[i] + bsR); \
        float z1 = sigm(acc1[i] + hZ[i] + bsZ); \
        float n1 = tanhf(acc2[i] + biN + r1*(hN[i] + bhN)); \
        float h = (1.f-z1)*n1 + z1*hold; \
        STW(p1 + (size_t)(b0w+(i))*512 + ng, pkh(h)); }
      E1(0,pk0) E1(1,pk1) E1(2,pk2) E1(3,pk3)
      #undef E1
    }
    gbar(slots, epoch, wg, tid, 3*t + 3);

    // ================= phase C =================
    if (role == 3){
      const uint* hp1 = hpk + 65536;
      f32x4 acc0={0,0,0,0};
      DECL_LOADS(hp1)
      RUN16(MS1)
      float s0 = S.wo2v[col]*fmaxf(acc0[0] + S.bo1v[col], 0.f);
      float s1 = S.wo2v[col]*fmaxf(acc0[1] + S.bo1v[col], 0.f);
      float s2 = S.wo2v[col]*fmaxf(acc0[2] + S.bo1v[col], 0.f);
      float s3 = S.wo2v[col]*fmaxf(acc0[3] + S.bo1v[col], 0.f);
      #pragma unroll
      for (int d = 1; d < 16; d <<= 1){
        s0 += __shfl_xor(s0, d);
        s1 += __shfl_xor(s1, d);
        s2 += __shfl_xor(s2, d);
        s3 += __shfl_xor(s3, d);
      }
      if (col == 0){
        float* rp = yout + (t&1)*2048 + j*64 + b0w;
        STW(rp + 0, s0); STW(rp + 1, s1); STW(rp + 2, s2); STW(rp + 3, s3);
      }
    }
    gbar(slots, epoch, wg, tid, 3*t + 4);
  }

  // ---------------- finale ----------------
  if (wg == 0 && tid < 64){
    float s = 0.f;
    const float* yp = yout + 2048 + tid;   // parity of t=1023 is 1
    #pragma unroll
    for (int jj = 0; jj < 32; ++jj) s += yp[jj*64];
    out[(size_t)tid*TT + 1023] = fmaxf(s + bo2v, 0.f);
  }
  #pragma unroll
  for (int k = 0; k < 2; ++k){
    int g = wg*512 + k*256 + tid;
    if (g < 32768) out[65536 + g] = unpk(hpk[g]);            // h0 final in buf0
    else           out[65536 + g] = unpk(hpk[65536 + (g - 32768)]);
  }
}

extern "C" void kernel_launch(void* const* d_in, const int* in_sizes, int n_in,
                              void* d_out, int out_size, void* d_ws, size_t ws_size,
                              hipStream_t stream){
  const float* ctx   = (const float*)d_in[0];
  const float* Wih0  = (const float*)d_in[2];
  const float* Whh0  = (const float*)d_in[3];
  const float* bih0  = (const float*)d_in[4];
  const float* bhh0  = (const float*)d_in[5];
  const float* Wih1  = (const float*)d_in[6];
  const float* Whh1  = (const float*)d_in[7];
  const float* bih1  = (const float*)d_in[8];
  const float* bhh1  = (const float*)d_in[9];
  const float* Wo1   = (const float*)d_in[10];
  const float* bo1   = (const float*)d_in[11];
  const float* Wo2   = (const float*)d_in[12];
  const float* bo2   = (const float*)d_in[13];

  (void)in_sizes; (void)n_in; (void)out_size; (void)ws_size;

  (void)hipFuncSetAttribute((const void*)decoder_rnn,
                            hipFuncAttributeMaxDynamicSharedMemorySize,
                            (int)sizeof(Smem));

  decoder_rnn<<<NWG, NT, sizeof(Smem), stream>>>(
      ctx, Wih0, Whh0, bih0, bhh0, Wih1, Whh1, bih1, bhh1,
      Wo1, bo1, Wo2, bo2, (float*)d_out, (float*)d_ws);
}

// Round 8
// 24974.142 us; speedup vs baseline: 1.1717x; 1.1717x over previous
//
#include <hip/hip_runtime.h>
#include <stdint.h>

// DecoderRNN R8: point-to-point flag pipeline (no per-step global barriers).
// 2-layer GRU, H=512, B=64, T=1024. 128 WGs x 256 threads, roles (wg>>5):
//   role 0: h0[t] = GRU0(h0[t-1], prev=y[t-1]); waits c0>=32t (pre-MFMA), c3>=32t (epilogue)
//   role 1: gh1[t] = h1[t-1] @ Whh1^T;          waits c2>=32t
//   role 2: h1[t] = GRU1(h0[t]@Wih1 + gh1[t]);  waits c0>=32(t+1), c1>=32(t+1)
//   role 3: y[t] partials from h1[t];           waits c2>=32(t+1)
// Arrival: fetch_add(counter, RELEASE, agent) by tid0 after __syncthreads (vmcnt
// drained per-wave by syncthreads). Consumers poll relaxed + acquire fence.
// Counters monotone (no reset); zeroed by WG0, published by one init gbar.
// Data path = R7: h packed (bf16hi<<16)|bf16lo, write-through relaxed stores.

#define NWG 128
#define NT  256
#define TT  1024

typedef unsigned short ushort;
typedef unsigned int   uint;
typedef __attribute__((ext_vector_type(8))) short short8;
typedef __attribute__((ext_vector_type(4))) float f32x4;
typedef __attribute__((ext_vector_type(4))) uint  uint4v;

struct __align__(16) Smem {
  ushort wpl[2][48*520];
  float  gictx[3*16*68];
  float  wcol[3][16];
  float  bsumR[16], bsumZ[16], binN[16], bhnN[16];
  float  bo1v[16], wo2v[16];
  float  prevS[64];
};

__device__ __forceinline__ float sigm(float x){ return 1.f/(1.f + expf(-x)); }
__device__ __forceinline__ float bf2f(ushort h){ return __uint_as_float(((uint)h)<<16); }
__device__ __forceinline__ ushort bfrnd(float x){
  uint u = __float_as_uint(x);
  return (ushort)((u + 0x7fffu + ((u>>16)&1u)) >> 16);
}
__device__ __forceinline__ float unpk(uint p){
  return bf2f((ushort)(p >> 16)) + bf2f((ushort)(p & 0xffffu));
}
__device__ __forceinline__ uint pkh(float h){
  ushort hb = bfrnd(h);
  ushort lb = bfrnd(h - bf2f(hb));
  return ((uint)hb << 16) | (uint)lb;
}
__device__ __forceinline__ short8 hi8(uint4v a, uint4v b){
  uint d0 = __builtin_amdgcn_perm(a.y, a.x, 0x07060302u);
  uint d1 = __builtin_amdgcn_perm(a.w, a.z, 0x07060302u);
  uint d2 = __builtin_amdgcn_perm(b.y, b.x, 0x07060302u);
  uint d3 = __builtin_amdgcn_perm(b.w, b.z, 0x07060302u);
  return __builtin_bit_cast(short8, (uint4v){d0,d1,d2,d3});
}
__device__ __forceinline__ short8 lo8(uint4v a, uint4v b){
  uint d0 = __builtin_amdgcn_perm(a.y, a.x, 0x05040100u);
  uint d1 = __builtin_amdgcn_perm(a.w, a.z, 0x05040100u);
  uint d2 = __builtin_amdgcn_perm(b.y, b.x, 0x05040100u);
  uint d3 = __builtin_amdgcn_perm(b.w, b.z, 0x05040100u);
  return __builtin_bit_cast(short8, (uint4v){d0,d1,d2,d3});
}
#define STW(p, v) __hip_atomic_store((p), (v), __ATOMIC_RELAXED, __HIP_MEMORY_SCOPE_AGENT)

// init-only global barrier (poison-safe epochs)
__device__ __forceinline__ void gbar(int* slots, int* epoch, int w, int tid, int e){
  __syncthreads();
  if (tid == 0)
    __hip_atomic_store(&slots[w], e, __ATOMIC_RELEASE, __HIP_MEMORY_SCOPE_AGENT);
  if (w == 0 && tid < 64){
    for(;;){
      int m0 = __hip_atomic_load(&slots[tid*2+0], __ATOMIC_RELAXED, __HIP_MEMORY_SCOPE_AGENT);
      int m1 = __hip_atomic_load(&slots[tid*2+1], __ATOMIC_RELAXED, __HIP_MEMORY_SCOPE_AGENT);
      if (__all(min(m0,m1) >= e)) break;
      __builtin_amdgcn_s_sleep(1);
    }
    if (tid == 0){
      __builtin_amdgcn_fence(__ATOMIC_ACQUIRE, "agent");
      __hip_atomic_store(epoch, e, __ATOMIC_RELEASE, __HIP_MEMORY_SCOPE_AGENT);
    }
  }
  if (tid == 0){
    while (__hip_atomic_load(epoch, __ATOMIC_RELAXED, __HIP_MEMORY_SCOPE_AGENT) < e)
      __builtin_amdgcn_s_sleep(1);
    __builtin_amdgcn_fence(__ATOMIC_ACQUIRE, "agent");
  }
  __syncthreads();
}

// point-to-point sync
__device__ __forceinline__ void arrive(int* c, int tid){
  __syncthreads();   // per-wave vmcnt drain: all WG stores issued/acked
  if (tid == 0)
    (void)__hip_atomic_fetch_add(c, 1, __ATOMIC_RELEASE, __HIP_MEMORY_SCOPE_AGENT);
}
__device__ __forceinline__ void waitge(int* c, int target, int tid){
  if (tid == 0){
    while (__hip_atomic_load(c, __ATOMIC_RELAXED, __HIP_MEMORY_SCOPE_AGENT) < target)
      __builtin_amdgcn_s_sleep(1);
    __builtin_amdgcn_fence(__ATOMIC_ACQUIRE, "agent");
  }
  __syncthreads();
}

#define LDONLY(P, i) \
  uint4v pa##i = *(const uint4v*)((P) + aoff + (i)*32); \
  uint4v pb##i = *(const uint4v*)((P) + aoff + (i)*32 + 4);
#define DECL_LOADS(P) LDONLY(P,0) LDONLY(P,1) LDONLY(P,2) LDONLY(P,3) \
  LDONLY(P,4) LDONLY(P,5) LDONLY(P,6) LDONLY(P,7) LDONLY(P,8) LDONLY(P,9) \
  LDONLY(P,10) LDONLY(P,11) LDONLY(P,12) LDONLY(P,13) LDONLY(P,14) LDONLY(P,15)

#define MS3(i) { \
  short8 AH_ = hi8(pa##i, pb##i); \
  short8 AL_ = lo8(pa##i, pb##i); \
  const int ko_ = (i)*32 + q*8; \
  short8 bh_ = *(const short8*)(&S.wpl[0][(col)*520 + ko_]); \
  short8 bl_ = *(const short8*)(&S.wpl[1][(col)*520 + ko_]); \
  acc0 = __builtin_amdgcn_mfma_f32_16x16x32_bf16(AH_, bh_, acc0, 0,0,0); \
  acc0 = __builtin_amdgcn_mfma_f32_16x16x32_bf16(AL_, bh_, acc0, 0,0,0); \
  acc0 = __builtin_amdgcn_mfma_f32_16x16x32_bf16(AH_, bl_, acc0, 0,0,0); \
  bh_ = *(const short8*)(&S.wpl[0][(16+col)*520 + ko_]); \
  bl_ = *(const short8*)(&S.wpl[1][(16+col)*520 + ko_]); \
  acc1 = __builtin_amdgcn_mfma_f32_16x16x32_bf16(AH_, bh_, acc1, 0,0,0); \
  acc1 = __builtin_amdgcn_mfma_f32_16x16x32_bf16(AL_, bh_, acc1, 0,0,0); \
  acc1 = __builtin_amdgcn_mfma_f32_16x16x32_bf16(AH_, bl_, acc1, 0,0,0); \
  bh_ = *(const short8*)(&S.wpl[0][(32+col)*520 + ko_]); \
  bl_ = *(const short8*)(&S.wpl[1][(32+col)*520 + ko_]); \
  acc2 = __builtin_amdgcn_mfma_f32_16x16x32_bf16(AH_, bh_, acc2, 0,0,0); \
  acc2 = __builtin_amdgcn_mfma_f32_16x16x32_bf16(AL_, bh_, acc2, 0,0,0); \
  acc2 = __builtin_amdgcn_mfma_f32_16x16x32_bf16(AH_, bl_, acc2, 0,0,0); }

#define MS1(i) { \
  short8 AH_ = hi8(pa##i, pb##i); \
  short8 AL_ = lo8(pa##i, pb##i); \
  const int ko_ = (i)*32 + q*8; \
  short8 bh_ = *(const short8*)(&S.wpl[0][(col)*520 + ko_]); \
  short8 bl_ = *(const short8*)(&S.wpl[1][(col)*520 + ko_]); \
  acc0 = __builtin_amdgcn_mfma_f32_16x16x32_bf16(AH_, bh_, acc0, 0,0,0); \
  acc0 = __builtin_amdgcn_mfma_f32_16x16x32_bf16(AL_, bh_, acc0, 0,0,0); \
  acc0 = __builtin_amdgcn_mfma_f32_16x16x32_bf16(AH_, bl_, acc0, 0,0,0); }

#define RUN16(M) M(0) M(1) M(2) M(3) M(4) M(5) M(6) M(7) \
                 M(8) M(9) M(10) M(11) M(12) M(13) M(14) M(15)

extern "C" __global__ void __launch_bounds__(NT, 1)
decoder_rnn(const float* __restrict__ ctx,   // [64][512]
            const float* __restrict__ Wih0,  // [1536][513] (row stride 513!)
            const float* __restrict__ Whh0,
            const float* __restrict__ bih0,
            const float* __restrict__ bhh0g,
            const float* __restrict__ Wih1,
            const float* __restrict__ Whh1,
            const float* __restrict__ bih1g,
            const float* __restrict__ bhh1g,
            const float* __restrict__ Wo1,
            const float* __restrict__ bo1g,
            const float* __restrict__ Wo2,
            const float* __restrict__ bo2g,
            float* __restrict__ out,         // [64*1024 y][65536 h_i]
            float* __restrict__ ws)
{
  extern __shared__ char smem_raw[];
  Smem& S = *reinterpret_cast<Smem*>(smem_raw);
  const int tid = threadIdx.x;
  const int wg  = blockIdx.x;

  uint*  hpk    = (uint*)ws;                 // h0pk 2x32768 | h1pk 32768
  float* gh1raw = (float*)ws + 98304;        // 32*3072
  float* yout   = (float*)ws + 196608;       // 2 x 2048
  int*   slots  = (int*)((float*)ws + 200704);
  int*   epoch  = slots + NWG;
  int*   cnt    = epoch + 63;                // 4 counters, 16-int (64B) stride

  const float bo2v = bo2g[0];

  // ---------------- init ----------------
  for (int i = wg*NT + tid; i < 32768; i += NWG*NT){
    STW(hpk + i, 0u);            // h0pk buf0
    STW(hpk + 65536 + i, 0u);    // h1pk
  }
  if (wg == 0 && tid < 4) cnt[16*tid] = 0;

  const int role = wg >> 5;
  const int j    = wg & 31;
  if (role != 3){
    const float* Wsrc = (role == 0) ? Whh0 : (role == 1) ? Whh1 : Wih1;
    for (int i = tid; i < 48*512; i += NT){
      int r = i >> 9, k = i & 511;
      int g = r >> 4, n = r & 15;
      float wv = Wsrc[(size_t)(g*512 + 16*j + n)*512 + k];
      ushort hh = bfrnd(wv);
      S.wpl[0][r*520 + k] = hh;
      S.wpl[1][r*520 + k] = bfrnd(wv - bf2f(hh));
    }
  } else {
    for (int i = tid; i < 16*512; i += NT){
      int r = i >> 9, k = i & 511;
      float wv = Wo1[(size_t)(16*j + r)*512 + k];
      ushort hh = bfrnd(wv);
      S.wpl[0][r*520 + k] = hh;
      S.wpl[1][r*520 + k] = bfrnd(wv - bf2f(hh));
    }
    if (tid < 16){ S.bo1v[tid] = bo1g[16*j + tid]; S.wo2v[tid] = Wo2[16*j + tid]; }
  }
  if (role == 0){
    if (tid < 48){
      int g = tid >> 4, n = tid & 15;
      S.wcol[g][n] = Wih0[(size_t)(g*512 + 16*j + n)*513 + 512];
    }
    if (tid < 16) S.bhnN[tid] = bhh0g[2*512 + 16*j + tid];
    for (int idx = tid; idx < 3072; idx += NT){
      int r = idx >> 6, b = idx & 63;
      int g = r >> 4, n = r & 15;
      int grow = g*512 + 16*j + n;
      const float* wr = Wih0 + (size_t)grow*513;
      const float* cx = ctx  + (size_t)b*512;
      float s = bih0[grow];
      if (g < 2) s += bhh0g[grow];
      #pragma unroll 4
      for (int k = 0; k < 512; ++k) s += wr[k]*cx[k];
      S.gictx[g*1088 + n*68 + b] = s;
    }
  }
  if (role == 2 && tid < 16){
    int n = tid;
    S.bsumR[n] = bih1g[16*j + n]       + bhh1g[16*j + n];
    S.bsumZ[n] = bih1g[512 + 16*j + n] + bhh1g[512 + 16*j + n];
    S.binN[n]  = bih1g[1024 + 16*j + n];
    S.bhnN[n]  = bhh1g[1024 + 16*j + n];
  }

  gbar(slots, epoch, wg, tid, 1);   // publishes zeros + weights staging

  int* c0 = cnt + 0;
  int* c1 = cnt + 16;
  int* c2 = cnt + 32;
  int* c3 = cnt + 48;

  const int v   = tid >> 6;
  const int l   = tid & 63;
  const int q   = l >> 4;
  const int col = l & 15;
  const int aoff = (16*v + col)*512 + q*8;
  const int b0w  = 16*v + 4*q;
  const int ng   = 16*j + col;

  if (role == 0){
    for (int t = 0; t < TT; ++t){
      const int r0 = t & 1, w0 = r0 ^ 1;
      waitge(c0, 32*t, tid);                 // h0[t-1] published
      const uint* rP = hpk + r0*32768;
      uint*       wP = hpk + w0*32768;
      f32x4 acc0={0,0,0,0}, acc1={0,0,0,0}, acc2={0,0,0,0};
      DECL_LOADS(rP)
      uint pk0 = rP[(b0w+0)*512+ng], pk1 = rP[(b0w+1)*512+ng],
           pk2 = rP[(b0w+2)*512+ng], pk3 = rP[(b0w+3)*512+ng];
      RUN16(MS3)
      waitge(c3, 32*t, tid);                 // y[t-1] partials published
      if (tid < 64){
        float s = 0.f;
        if (t > 0){
          const float* yp = yout + ((t-1)&1)*2048 + tid;
          #pragma unroll
          for (int jj = 0; jj < 32; ++jj) s += yp[jj*64];
        }
        float pv = fmaxf(s + bo2v, 0.f);
        S.prevS[tid] = pv;
        if (wg == 0 && t > 0) out[(size_t)tid*TT + (t-1)] = pv;
      }
      __syncthreads();
      f32x4 pv4 = *(const f32x4*)&S.prevS[b0w];
      f32x4 gR = *(const f32x4*)&S.gictx[0*1088 + col*68 + b0w];
      f32x4 gZ = *(const f32x4*)&S.gictx[1*1088 + col*68 + b0w];
      f32x4 gN = *(const f32x4*)&S.gictx[2*1088 + col*68 + b0w];
      float wc0 = S.wcol[0][col], wc1 = S.wcol[1][col], wc2 = S.wcol[2][col];
      float bhn = S.bhnN[col];
      #define E0(i, PK) { \
        float hold = unpk(PK); \
        float rr = sigm(gR[i] + pv4[i]*wc0 + acc0[i]); \
        float zz = sigm(gZ[i] + pv4[i]*wc1 + acc1[i]); \
        float nn = tanhf(gN[i] + pv4[i]*wc2 + rr*(acc2[i] + bhn)); \
        float h = (1.f-zz)*nn + zz*hold; \
        STW(wP + (size_t)(b0w+(i))*512 + ng, pkh(h)); }
      E0(0,pk0) E0(1,pk1) E0(2,pk2) E0(3,pk3)
      #undef E0
      arrive(c0, tid);
    }
  } else if (role == 1){
    const uint* hp1 = hpk + 65536;
    for (int t = 0; t < TT; ++t){
      waitge(c2, 32*t, tid);                 // h1[t-1] published
      f32x4 acc0={0,0,0,0}, acc1={0,0,0,0}, acc2={0,0,0,0};
      DECL_LOADS(hp1)
      RUN16(MS3)
      float* gp = gh1raw + (size_t)j*3072 + v*256 + l*4;
      #pragma unroll
      for (int e = 0; e < 4; ++e){
        STW(gp + e,        acc0[e]);
        STW(gp + 1024 + e, acc1[e]);
        STW(gp + 2048 + e, acc2[e]);
      }
      arrive(c1, tid);
    }
  } else if (role == 2){
    uint* p1 = hpk + 65536;
    for (int t = 0; t < TT; ++t){
      const int w0 = (t & 1) ^ 1;
      waitge(c0, 32*(t+1), tid);             // h0[t] published
      const uint* rP = hpk + w0*32768;
      f32x4 acc0={0,0,0,0}, acc1={0,0,0,0}, acc2={0,0,0,0};
      DECL_LOADS(rP)
      uint pk0 = p1[(b0w+0)*512+ng], pk1 = p1[(b0w+1)*512+ng],
           pk2 = p1[(b0w+2)*512+ng], pk3 = p1[(b0w+3)*512+ng];
      RUN16(MS3)
      waitge(c1, 32*(t+1), tid);             // gh1[t] published (usually ready)
      const float* gp = gh1raw + (size_t)j*3072 + v*256 + l*4;
      f32x4 hR = *(const f32x4*)(gp + 0);
      f32x4 hZ = *(const f32x4*)(gp + 1024);
      f32x4 hN = *(const f32x4*)(gp + 2048);
      float bsR = S.bsumR[col], bsZ = S.bsumZ[col], biN = S.binN[col], bhN = S.bhnN[col];
      #define E1(i, PK) { \
        float hold = unpk(PK); \
        float r1 = sigm(acc0[i] + hR[i] + bsR); \
        float z1 = sigm(acc1[i] + hZ[i] + bsZ); \
        float n1 = tanhf(acc2[i] + biN + r1*(hN[i] + bhN)); \
        float h = (1.f-z1)*n1 + z1*hold; \
        STW(p1 + (size_t)(b0w+(i))*512 + ng, pkh(h)); }
      E1(0,pk0) E1(1,pk1) E1(2,pk2) E1(3,pk3)
      #undef E1
      arrive(c2, tid);
    }
  } else {
    const uint* hp1 = hpk + 65536;
    for (int t = 0; t < TT; ++t){
      waitge(c2, 32*(t+1), tid);             // h1[t] published
      f32x4 acc0={0,0,0,0};
      DECL_LOADS(hp1)
      RUN16(MS1)
      float s0 = S.wo2v[col]*fmaxf(acc0[0] + S.bo1v[col], 0.f);
      float s1 = S.wo2v[col]*fmaxf(acc0[1] + S.bo1v[col], 0.f);
      float s2 = S.wo2v[col]*fmaxf(acc0[2] + S.bo1v[col], 0.f);
      float s3 = S.wo2v[col]*fmaxf(acc0[3] + S.bo1v[col], 0.f);
      #pragma unroll
      for (int d = 1; d < 16; d <<= 1){
        s0 += __shfl_xor(s0, d);
        s1 += __shfl_xor(s1, d);
        s2 += __shfl_xor(s2, d);
        s3 += __shfl_xor(s3, d);
      }
      if (col == 0){
        float* rp = yout + (t&1)*2048 + j*64 + b0w;
        STW(rp + 0, s0); STW(rp + 1, s1); STW(rp + 2, s2); STW(rp + 3, s3);
      }
      arrive(c3, tid);
    }
  }

  // ---------------- finale ----------------
  waitge(c0, 32*TT, tid);
  waitge(c2, 32*TT, tid);
  if (wg == 0){
    waitge(c3, 32*TT, tid);
    if (tid < 64){
      float s = 0.f;
      const float* yp = yout + 2048 + tid;   // parity of t=1023 is 1
      #pragma unroll
      for (int jj = 0; jj < 32; ++jj) s += yp[jj*64];
      out[(size_t)tid*TT + 1023] = fmaxf(s + bo2v, 0.f);
    }
  }
  #pragma unroll
  for (int k = 0; k < 2; ++k){
    int g = wg*512 + k*256 + tid;
    if (g < 32768) out[65536 + g] = unpk(hpk[g]);            // h0 final in buf0
    else           out[65536 + g] = unpk(hpk[65536 + (g - 32768)]);
  }
}

extern "C" void kernel_launch(void* const* d_in, const int* in_sizes, int n_in,
                              void* d_out, int out_size, void* d_ws, size_t ws_size,
                              hipStream_t stream){
  const float* ctx   = (const float*)d_in[0];
  const float* Wih0  = (const float*)d_in[2];
  const float* Whh0  = (const float*)d_in[3];
  const float* bih0  = (const float*)d_in[4];
  const float* bhh0  = (const float*)d_in[5];
  const float* Wih1  = (const float*)d_in[6];
  const float* Whh1  = (const float*)d_in[7];
  const float* bih1  = (const float*)d_in[8];
  const float* bhh1  = (const float*)d_in[9];
  const float* Wo1   = (const float*)d_in[10];
  const float* bo1   = (const float*)d_in[11];
  const float* Wo2   = (const float*)d_in[12];
  const float* bo2   = (const float*)d_in[13];

  (void)in_sizes; (void)n_in; (void)out_size; (void)ws_size;

  (void)hipFuncSetAttribute((const void*)decoder_rnn,
                            hipFuncAttributeMaxDynamicSharedMemorySize,
                            (int)sizeof(Smem));

  decoder_rnn<<<NWG, NT, sizeof(Smem), stream>>>(
      ctx, Wih0, Whh0, bih0, bhh0, Wih1, Whh1, bih1, bhh1,
      Wo1, bo1, Wo2, bo2, (float*)d_out, (float*)d_ws);
}

// Round 9
// 23931.758 us; speedup vs baseline: 1.2227x; 1.0436x over previous
//
#include <hip/hip_runtime.h>
#include <stdint.h>

// DecoderRNN R9: R8's p2p pipeline + LLC-resident data path.
// Key change vs R8: cross-WG stores are relaxed agent-scope atomic SWAPS
// (execute at the LLC, line stays dirty in LLC -> consumer loads hit LLC, not
// HBM), and arrive() drops the release fence (no per-arrival buffer_wbl2):
// explicit s_waitcnt(0) + syncthreads drains swaps to LLC before the relaxed
// fetch_add publishes. waitge keeps the acquire fence (plain consumer loads
// need the L1/L2 inv). Roles/counters/lifetimes identical to R8.

#define NWG 128
#define NT  256
#define TT  1024

typedef unsigned short ushort;
typedef unsigned int   uint;
typedef __attribute__((ext_vector_type(8))) short short8;
typedef __attribute__((ext_vector_type(4))) float f32x4;
typedef __attribute__((ext_vector_type(4))) uint  uint4v;

struct __align__(16) Smem {
  ushort wpl[2][48*520];
  float  gictx[3*16*68];
  float  wcol[3][16];
  float  bsumR[16], bsumZ[16], binN[16], bhnN[16];
  float  bo1v[16], wo2v[16];
  float  prevS[64];
};

__device__ __forceinline__ float sigm(float x){ return 1.f/(1.f + expf(-x)); }
__device__ __forceinline__ float bf2f(ushort h){ return __uint_as_float(((uint)h)<<16); }
__device__ __forceinline__ ushort bfrnd(float x){
  uint u = __float_as_uint(x);
  return (ushort)((u + 0x7fffu + ((u>>16)&1u)) >> 16);
}
__device__ __forceinline__ float unpk(uint p){
  return bf2f((ushort)(p >> 16)) + bf2f((ushort)(p & 0xffffu));
}
__device__ __forceinline__ uint pkh(float h){
  ushort hb = bfrnd(h);
  ushort lb = bfrnd(h - bf2f(hb));
  return ((uint)hb << 16) | (uint)lb;
}
__device__ __forceinline__ short8 hi8(uint4v a, uint4v b){
  uint d0 = __builtin_amdgcn_perm(a.y, a.x, 0x07060302u);
  uint d1 = __builtin_amdgcn_perm(a.w, a.z, 0x07060302u);
  uint d2 = __builtin_amdgcn_perm(b.y, b.x, 0x07060302u);
  uint d3 = __builtin_amdgcn_perm(b.w, b.z, 0x07060302u);
  return __builtin_bit_cast(short8, (uint4v){d0,d1,d2,d3});
}
__device__ __forceinline__ short8 lo8(uint4v a, uint4v b){
  uint d0 = __builtin_amdgcn_perm(a.y, a.x, 0x05040100u);
  uint d1 = __builtin_amdgcn_perm(a.w, a.z, 0x05040100u);
  uint d2 = __builtin_amdgcn_perm(b.y, b.x, 0x05040100u);
  uint d3 = __builtin_amdgcn_perm(b.w, b.z, 0x05040100u);
  return __builtin_bit_cast(short8, (uint4v){d0,d1,d2,d3});
}
// atomic-swap store: executes at LLC, allocates line in LLC (not HBM write-through)
#define SWP(p, v) (void)__hip_atomic_exchange((uint*)(p), (uint)(v), __ATOMIC_RELAXED, __HIP_MEMORY_SCOPE_AGENT)
#define SWPF(p, v) SWP((p), __float_as_uint(v))

// init-only global barrier (poison-safe epochs; release here flushes init stores)
__device__ __forceinline__ void gbar(int* slots, int* epoch, int w, int tid, int e){
  __syncthreads();
  if (tid == 0)
    __hip_atomic_store(&slots[w], e, __ATOMIC_RELEASE, __HIP_MEMORY_SCOPE_AGENT);
  if (w == 0 && tid < 64){
    for(;;){
      int m0 = __hip_atomic_load(&slots[tid*2+0], __ATOMIC_RELAXED, __HIP_MEMORY_SCOPE_AGENT);
      int m1 = __hip_atomic_load(&slots[tid*2+1], __ATOMIC_RELAXED, __HIP_MEMORY_SCOPE_AGENT);
      if (__all(min(m0,m1) >= e)) break;
      __builtin_amdgcn_s_sleep(1);
    }
    if (tid == 0){
      __builtin_amdgcn_fence(__ATOMIC_ACQUIRE, "agent");
      __hip_atomic_store(epoch, e, __ATOMIC_RELEASE, __HIP_MEMORY_SCOPE_AGENT);
    }
  }
  if (tid == 0){
    while (__hip_atomic_load(epoch, __ATOMIC_RELAXED, __HIP_MEMORY_SCOPE_AGENT) < e)
      __builtin_amdgcn_s_sleep(1);
    __builtin_amdgcn_fence(__ATOMIC_ACQUIRE, "agent");
  }
  __syncthreads();
}

// arrive: drain swaps to LLC (vmcnt 0) on every wave, then relaxed bump (NO wbl2)
__device__ __forceinline__ void arrive(int* c, int tid){
  __builtin_amdgcn_s_waitcnt(0);
  __syncthreads();
  if (tid == 0)
    (void)__hip_atomic_fetch_add(c, 1, __ATOMIC_RELAXED, __HIP_MEMORY_SCOPE_AGENT);
}
__device__ __forceinline__ void waitge(int* c, int target, int tid){
  if (tid == 0){
    while (__hip_atomic_load(c, __ATOMIC_RELAXED, __HIP_MEMORY_SCOPE_AGENT) < target)
      __builtin_amdgcn_s_sleep(1);
    __builtin_amdgcn_fence(__ATOMIC_ACQUIRE, "agent");   // inv L1/L2 -> loads see LLC
  }
  __syncthreads();
}

#define LDONLY(P, i) \
  uint4v pa##i = *(const uint4v*)((P) + aoff + (i)*32); \
  uint4v pb##i = *(const uint4v*)((P) + aoff + (i)*32 + 4);
#define DECL_LOADS(P) LDONLY(P,0) LDONLY(P,1) LDONLY(P,2) LDONLY(P,3) \
  LDONLY(P,4) LDONLY(P,5) LDONLY(P,6) LDONLY(P,7) LDONLY(P,8) LDONLY(P,9) \
  LDONLY(P,10) LDONLY(P,11) LDONLY(P,12) LDONLY(P,13) LDONLY(P,14) LDONLY(P,15)

#define MS3(i) { \
  short8 AH_ = hi8(pa##i, pb##i); \
  short8 AL_ = lo8(pa##i, pb##i); \
  const int ko_ = (i)*32 + q*8; \
  short8 bh_ = *(const short8*)(&S.wpl[0][(col)*520 + ko_]); \
  short8 bl_ = *(const short8*)(&S.wpl[1][(col)*520 + ko_]); \
  acc0 = __builtin_amdgcn_mfma_f32_16x16x32_bf16(AH_, bh_, acc0, 0,0,0); \
  acc0 = __builtin_amdgcn_mfma_f32_16x16x32_bf16(AL_, bh_, acc0, 0,0,0); \
  acc0 = __builtin_amdgcn_mfma_f32_16x16x32_bf16(AH_, bl_, acc0, 0,0,0); \
  bh_ = *(const short8*)(&S.wpl[0][(16+col)*520 + ko_]); \
  bl_ = *(const short8*)(&S.wpl[1][(16+col)*520 + ko_]); \
  acc1 = __builtin_amdgcn_mfma_f32_16x16x32_bf16(AH_, bh_, acc1, 0,0,0); \
  acc1 = __builtin_amdgcn_mfma_f32_16x16x32_bf16(AL_, bh_, acc1, 0,0,0); \
  acc1 = __builtin_amdgcn_mfma_f32_16x16x32_bf16(AH_, bl_, acc1, 0,0,0); \
  bh_ = *(const short8*)(&S.wpl[0][(32+col)*520 + ko_]); \
  bl_ = *(const short8*)(&S.wpl[1][(32+col)*520 + ko_]); \
  acc2 = __builtin_amdgcn_mfma_f32_16x16x32_bf16(AH_, bh_, acc2, 0,0,0); \
  acc2 = __builtin_amdgcn_mfma_f32_16x16x32_bf16(AL_, bh_, acc2, 0,0,0); \
  acc2 = __builtin_amdgcn_mfma_f32_16x16x32_bf16(AH_, bl_, acc2, 0,0,0); }

#define MS1(i) { \
  short8 AH_ = hi8(pa##i, pb##i); \
  short8 AL_ = lo8(pa##i, pb##i); \
  const int ko_ = (i)*32 + q*8; \
  short8 bh_ = *(const short8*)(&S.wpl[0][(col)*520 + ko_]); \
  short8 bl_ = *(const short8*)(&S.wpl[1][(col)*520 + ko_]); \
  acc0 = __builtin_amdgcn_mfma_f32_16x16x32_bf16(AH_, bh_, acc0, 0,0,0); \
  acc0 = __builtin_amdgcn_mfma_f32_16x16x32_bf16(AL_, bh_, acc0, 0,0,0); \
  acc0 = __builtin_amdgcn_mfma_f32_16x16x32_bf16(AH_, bl_, acc0, 0,0,0); }

#define RUN16(M) M(0) M(1) M(2) M(3) M(4) M(5) M(6) M(7) \
                 M(8) M(9) M(10) M(11) M(12) M(13) M(14) M(15)

extern "C" __global__ void __launch_bounds__(NT, 1)
decoder_rnn(const float* __restrict__ ctx,   // [64][512]
            const float* __restrict__ Wih0,  // [1536][513] (row stride 513!)
            const float* __restrict__ Whh0,
            const float* __restrict__ bih0,
            const float* __restrict__ bhh0g,
            const float* __restrict__ Wih1,
            const float* __restrict__ Whh1,
            const float* __restrict__ bih1g,
            const float* __restrict__ bhh1g,
            const float* __restrict__ Wo1,
            const float* __restrict__ bo1g,
            const float* __restrict__ Wo2,
            const float* __restrict__ bo2g,
            float* __restrict__ out,         // [64*1024 y][65536 h_i]
            float* __restrict__ ws)
{
  extern __shared__ char smem_raw[];
  Smem& S = *reinterpret_cast<Smem*>(smem_raw);
  const int tid = threadIdx.x;
  const int wg  = blockIdx.x;

  uint*  hpk    = (uint*)ws;                 // h0pk 2x32768 | h1pk 32768
  float* gh1raw = (float*)ws + 98304;        // 32*3072
  float* yout   = (float*)ws + 196608;       // 2 x 2048
  int*   slots  = (int*)((float*)ws + 200704);
  int*   epoch  = slots + NWG;
  int*   cnt    = epoch + 63;                // 4 counters, 64B stride

  const float bo2v = bo2g[0];

  // ---------------- init (swaps -> LLC-resident zeros) ----------------
  for (int i = wg*NT + tid; i < 32768; i += NWG*NT){
    SWP(hpk + i, 0u);
    SWP(hpk + 65536 + i, 0u);
  }
  if (wg == 0 && tid < 4) cnt[16*tid] = 0;

  const int role = wg >> 5;
  const int j    = wg & 31;
  if (role != 3){
    const float* Wsrc = (role == 0) ? Whh0 : (role == 1) ? Whh1 : Wih1;
    for (int i = tid; i < 48*512; i += NT){
      int r = i >> 9, k = i & 511;
      int g = r >> 4, n = r & 15;
      float wv = Wsrc[(size_t)(g*512 + 16*j + n)*512 + k];
      ushort hh = bfrnd(wv);
      S.wpl[0][r*520 + k] = hh;
      S.wpl[1][r*520 + k] = bfrnd(wv - bf2f(hh));
    }
  } else {
    for (int i = tid; i < 16*512; i += NT){
      int r = i >> 9, k = i & 511;
      float wv = Wo1[(size_t)(16*j + r)*512 + k];
      ushort hh = bfrnd(wv);
      S.wpl[0][r*520 + k] = hh;
      S.wpl[1][r*520 + k] = bfrnd(wv - bf2f(hh));
    }
    if (tid < 16){ S.bo1v[tid] = bo1g[16*j + tid]; S.wo2v[tid] = Wo2[16*j + tid]; }
  }
  if (role == 0){
    if (tid < 48){
      int g = tid >> 4, n = tid & 15;
      S.wcol[g][n] = Wih0[(size_t)(g*512 + 16*j + n)*513 + 512];
    }
    if (tid < 16) S.bhnN[tid] = bhh0g[2*512 + 16*j + tid];
    for (int idx = tid; idx < 3072; idx += NT){
      int r = idx >> 6, b = idx & 63;
      int g = r >> 4, n = r & 15;
      int grow = g*512 + 16*j + n;
      const float* wr = Wih0 + (size_t)grow*513;
      const float* cx = ctx  + (size_t)b*512;
      float s = bih0[grow];
      if (g < 2) s += bhh0g[grow];
      #pragma unroll 4
      for (int k = 0; k < 512; ++k) s += wr[k]*cx[k];
      S.gictx[g*1088 + n*68 + b] = s;
    }
  }
  if (role == 2 && tid < 16){
    int n = tid;
    S.bsumR[n] = bih1g[16*j + n]       + bhh1g[16*j + n];
    S.bsumZ[n] = bih1g[512 + 16*j + n] + bhh1g[512 + 16*j + n];
    S.binN[n]  = bih1g[1024 + 16*j + n];
    S.bhnN[n]  = bhh1g[1024 + 16*j + n];
  }

  gbar(slots, epoch, wg, tid, 1);

  int* c0 = cnt + 0;
  int* c1 = cnt + 16;
  int* c2 = cnt + 32;
  int* c3 = cnt + 48;

  const int v   = tid >> 6;
  const int l   = tid & 63;
  const int q   = l >> 4;
  const int col = l & 15;
  const int aoff = (16*v + col)*512 + q*8;
  const int b0w  = 16*v + 4*q;
  const int ng   = 16*j + col;

  if (role == 0){
    for (int t = 0; t < TT; ++t){
      const int r0 = t & 1, w0 = r0 ^ 1;
      waitge(c0, 32*t, tid);                 // h0[t-1] published (peers)
      const uint* rP = hpk + r0*32768;
      uint*       wP = hpk + w0*32768;
      f32x4 acc0={0,0,0,0}, acc1={0,0,0,0}, acc2={0,0,0,0};
      DECL_LOADS(rP)
      uint pk0 = rP[(b0w+0)*512+ng], pk1 = rP[(b0w+1)*512+ng],
           pk2 = rP[(b0w+2)*512+ng], pk3 = rP[(b0w+3)*512+ng];
      RUN16(MS3)
      waitge(c3, 32*t, tid);                 // y[t-1] partials published
      if (tid < 64){
        float s = 0.f;
        if (t > 0){
          const float* yp = yout + ((t-1)&1)*2048 + tid;
          #pragma unroll
          for (int jj = 0; jj < 32; ++jj) s += yp[jj*64];
        }
        float pv = fmaxf(s + bo2v, 0.f);
        S.prevS[tid] = pv;
        if (wg == 0 && t > 0) out[(size_t)tid*TT + (t-1)] = pv;
      }
      __syncthreads();
      f32x4 pv4 = *(const f32x4*)&S.prevS[b0w];
      f32x4 gR = *(const f32x4*)&S.gictx[0*1088 + col*68 + b0w];
      f32x4 gZ = *(const f32x4*)&S.gictx[1*1088 + col*68 + b0w];
      f32x4 gN = *(const f32x4*)&S.gictx[2*1088 + col*68 + b0w];
      float wc0 = S.wcol[0][col], wc1 = S.wcol[1][col], wc2 = S.wcol[2][col];
      float bhn = S.bhnN[col];
      #define E0(i, PK) { \
        float hold = unpk(PK); \
        float rr = sigm(gR[i] + pv4[i]*wc0 + acc0[i]); \
        float zz = sigm(gZ[i] + pv4[i]*wc1 + acc1[i]); \
        float nn = tanhf(gN[i] + pv4[i]*wc2 + rr*(acc2[i] + bhn)); \
        float h = (1.f-zz)*nn + zz*hold; \
        SWP(wP + (size_t)(b0w+(i))*512 + ng, pkh(h)); }
      E0(0,pk0) E0(1,pk1) E0(2,pk2) E0(3,pk3)
      #undef E0
      arrive(c0, tid);
    }
  } else if (role == 1){
    const uint* hp1 = hpk + 65536;
    for (int t = 0; t < TT; ++t){
      waitge(c2, 32*t, tid);                 // h1[t-1] published
      f32x4 acc0={0,0,0,0}, acc1={0,0,0,0}, acc2={0,0,0,0};
      DECL_LOADS(hp1)
      RUN16(MS3)
      float* gp = gh1raw + (size_t)j*3072 + v*256 + l*4;
      #pragma unroll
      for (int e = 0; e < 4; ++e){
        SWPF(gp + e,        acc0[e]);
        SWPF(gp + 1024 + e, acc1[e]);
        SWPF(gp + 2048 + e, acc2[e]);
      }
      arrive(c1, tid);
    }
  } else if (role == 2){
    uint* p1 = hpk + 65536;
    for (int t = 0; t < TT; ++t){
      const int w0 = (t & 1) ^ 1;
      waitge(c0, 32*(t+1), tid);             // h0[t] published
      const uint* rP = hpk + w0*32768;
      f32x4 acc0={0,0,0,0}, acc1={0,0,0,0}, acc2={0,0,0,0};
      DECL_LOADS(rP)
      uint pk0 = p1[(b0w+0)*512+ng], pk1 = p1[(b0w+1)*512+ng],
           pk2 = p1[(b0w+2)*512+ng], pk3 = p1[(b0w+3)*512+ng];
      RUN16(MS3)
      waitge(c1, 32*(t+1), tid);             // gh1[t] published (usually ready)
      const float* gp = gh1raw + (size_t)j*3072 + v*256 + l*4;
      f32x4 hR = *(const f32x4*)(gp + 0);
      f32x4 hZ = *(const f32x4*)(gp + 1024);
      f32x4 hN = *(const f32x4*)(gp + 2048);
      float bsR = S.bsumR[col], bsZ = S.bsumZ[col], biN = S.binN[col], bhN = S.bhnN[col];
      #define E1(i, PK) { \
        float hold = unpk(PK); \
        float r1 = sigm(acc0[i] + hR[i] + bsR); \
        float z1 = sigm(acc1[i] + hZ[i] + bsZ); \
        float n1 = tanhf(acc2[i] + biN + r1*(hN[i] + bhN)); \
        float h = (1.f-z1)*n1 + z1*hold; \
        SWP(p1 + (size_t)(b0w+(i))*512 + ng, pkh(h)); }
      E1(0,pk0) E1(1,pk1) E1(2,pk2) E1(3,pk3)
      #undef E1
      arrive(c2, tid);
    }
  } else {
    const uint* hp1 = hpk + 65536;
    for (int t = 0; t < TT; ++t){
      waitge(c2, 32*(t+1), tid);             // h1[t] published
      f32x4 acc0={0,0,0,0};
      DECL_LOADS(hp1)
      RUN16(MS1)
      float s0 = S.wo2v[col]*fmaxf(acc0[0] + S.bo1v[col], 0.f);
      float s1 = S.wo2v[col]*fmaxf(acc0[1] + S.bo1v[col], 0.f);
      float s2 = S.wo2v[col]*fmaxf(acc0[2] + S.bo1v[col], 0.f);
      float s3 = S.wo2v[col]*fmaxf(acc0[3] + S.bo1v[col], 0.f);
      #pragma unroll
      for (int d = 1; d < 16; d <<= 1){
        s0 += __shfl_xor(s0, d);
        s1 += __shfl_xor(s1, d);
        s2 += __shfl_xor(s2, d);
        s3 += __shfl_xor(s3, d);
      }
      if (col == 0){
        float* rp = yout + (t&1)*2048 + j*64 + b0w;
        SWPF(rp + 0, s0); SWPF(rp + 1, s1); SWPF(rp + 2, s2); SWPF(rp + 3, s3);
      }
      arrive(c3, tid);
    }
  }

  // ---------------- finale ----------------
  waitge(c0, 32*TT, tid);
  waitge(c2, 32*TT, tid);
  if (wg == 0){
    waitge(c3, 32*TT, tid);
    if (tid < 64){
      float s = 0.f;
      const float* yp = yout + 2048 + tid;   // parity of t=1023 is 1
      #pragma unroll
      for (int jj = 0; jj < 32; ++jj) s += yp[jj*64];
      out[(size_t)tid*TT + 1023] = fmaxf(s + bo2v, 0.f);
    }
  }
  #pragma unroll
  for (int k = 0; k < 2; ++k){
    int g = wg*512 + k*256 + tid;
    if (g < 32768) out[65536 + g] = unpk(hpk[g]);            // h0 final in buf0
    else           out[65536 + g] = unpk(hpk[65536 + (g - 32768)]);
  }
}

extern "C" void kernel_launch(void* const* d_in, const int* in_sizes, int n_in,
                              void* d_out, int out_size, void* d_ws, size_t ws_size,
                              hipStream_t stream){
  const float* ctx   = (const float*)d_in[0];
  const float* Wih0  = (const float*)d_in[2];
  const float* Whh0  = (const float*)d_in[3];
  const float* bih0  = (const float*)d_in[4];
  const float* bhh0  = (const float*)d_in[5];
  const float* Wih1  = (const float*)d_in[6];
  const float* Whh1  = (const float*)d_in[7];
  const float* bih1  = (const float*)d_in[8];
  const float* bhh1  = (const float*)d_in[9];
  const float* Wo1   = (const float*)d_in[10];
  const float* bo1   = (const float*)d_in[11];
  const float* Wo2   = (const float*)d_in[12];
  const float* bo2   = (const float*)d_in[13];

  (void)in_sizes; (void)n_in; (void)out_size; (void)ws_size;

  (void)hipFuncSetAttribute((const void*)decoder_rnn,
                            hipFuncAttributeMaxDynamicSharedMemorySize,
                            (int)sizeof(Smem));

  decoder_rnn<<<NWG, NT, sizeof(Smem), stream>>>(
      ctx, Wih0, Whh0, bih0, bhh0, Wih1, Whh1, bih1, bhh1,
      Wo1, bo1, Wo2, bo2, (float*)d_out, (float*)d_ws);
}